// Round 5
// baseline (465.333 us; speedup 1.0000x reference)
//
#include <hip/hip_runtime.h>
#include <math.h>

#define TSTEPS 512
#define RPB 8
#define L2E  1.4426950408889634f
#define L2E2 2.8853900817779268f   // 2*log2(e)

typedef __attribute__((ext_vector_type(4))) short short4v;
typedef __attribute__((ext_vector_type(8))) short short8;
typedef __attribute__((ext_vector_type(4))) float f32x4;
typedef __bf16 bf16x8 __attribute__((ext_vector_type(8)));

__device__ __forceinline__ short f2bf(float f) {            // RNE float->bf16
    union { float f; unsigned u; } v; v.f = f;
    return (short)((v.u + 0x7FFFu + ((v.u >> 16) & 1u)) >> 16);
}
__device__ __forceinline__ unsigned pkbf(float lo, float hi) {  // HW RNE pack
    unsigned r;
    asm("v_cvt_pk_bf16_f32 %0, %1, %2" : "=v"(r) : "v"(lo), "v"(hi));
    return r;
}
__device__ __forceinline__ float rcp_f(float x) { return __builtin_amdgcn_rcpf(x); }
__device__ __forceinline__ float ex2(float x)   { return __builtin_amdgcn_exp2f(x); }
__device__ __forceinline__ float sigm_p(float v) { return rcp_f(1.0f + ex2(-v)); }   // v = x*log2e
__device__ __forceinline__ float tanh_p(float v) {                                    // v = x*2log2e
    return fmaf(-2.0f, rcp_f(1.0f + ex2(v)), 1.0f);        // 1 - 2/(1+e^{2x})
}
__device__ __forceinline__ f32x4 mfma16(bf16x8 a, bf16x8 b, f32x4 c) {
    return __builtin_amdgcn_mfma_f32_16x16x32_bf16(a, b, c, 0, 0, 0);
}

// 256 blocks x 256 threads (4 waves, 1/SIMD). Both layers merged into ONE
// 16x16 MFMA tile via block-diagonal K-packing (K=224), A rows:
//   rows 0-7  = [x_t (32) | h0^{t-1} (64) | 0 (128)]        -> L0 step t
//   rows 8-15 = [0 (96)   | h0^{t-1} (64) | h1^{t-2} (64)]  -> L1 step t-1
// THIS ROUND: rocprof shows MFMA-busy + VALU-busy + fixed latency == wall
// time (zero pipe overlap): the scheduler clusters all 28 MFMAs then runs
// the 40 transcendentals serially after. Force the interleave with
// sched_group_barrier per step region: {7 ds_read} -> {16 MFMA = 4 x-MFMAs
// + G/I chains} -> 6 x {2 MFMA (F/O pair), 5 VALU (g/i act ops)}. Per-acc
// chunk order 0..6 unchanged -> bit-identical. Also: lean barrier
// (s_waitcnt lgkmcnt(0) + raw s_barrier) instead of __syncthreads, so the
// x-prefetch global loads are NOT drained at the step barrier (vmcnt free
// to span steps). Branches (PREF/XST) are at region edges so the main body
// is one scheduling region.
#define SGB __builtin_amdgcn_sched_group_barrier

#define STEPB(SUB, PREF, XST, FRZ, XNXT) do {                           \
    if (PREF) {                                                         \
        xr0 = *(const float4*)(xp);                                     \
        xr1 = *(const float4*)(xp + 16);                                \
    }                                                                   \
    const short* haS_ = ((SUB) & 1) ? haB : haA;                        \
    const short* hcS_ = ((SUB) & 1) ? hcB : hcA;                        \
    const bf16x8 a1 = *(const bf16x8*)(haS_ + oH1);                     \
    const bf16x8 a2 = *(const bf16x8*)(haS_ + oH1 + 32);                \
    const bf16x8 a3 = *(const bf16x8*)(haS_ + oH2);                     \
    const bf16x8 a4 = *(const bf16x8*)(haS_ + oH2 + 32);                \
    const bf16x8 a5 = *(const bf16x8*)(hcS_ + oH2);                     \
    const bf16x8 a6 = *(const bf16x8*)(hcS_ + oH2 + 32);                \
    f32x4 AG = {b2, b2, b2, b2}, AI = {b0, b0, b0, b0},                 \
          AF = {b1, b1, b1, b1}, AO = {b3, b3, b3, b3};                 \
    AG = mfma16(a0c, B2_0, AG); AI = mfma16(a0c, B0_0, AI);             \
    AF = mfma16(a0c, B1_0, AF); AO = mfma16(a0c, B3_0, AO);             \
    AG = mfma16(a1, B2_1, AG); AI = mfma16(a1, B0_1, AI);               \
    AG = mfma16(a2, B2_2, AG); AI = mfma16(a2, B0_2, AI);               \
    AG = mfma16(a3, B2_3, AG); AI = mfma16(a3, B0_3, AI);               \
    AG = mfma16(a4, B2_4, AG); AI = mfma16(a4, B0_4, AI);               \
    AG = mfma16(a5, B2_5, AG); AI = mfma16(a5, B0_5, AI);               \
    AG = mfma16(a6, B2_6, AG); AI = mfma16(a6, B0_6, AI);               \
    const float gv0 = tanh_p(AG[0]), gv1 = tanh_p(AG[1]);               \
    const float gv2 = tanh_p(AG[2]), gv3 = tanh_p(AG[3]);               \
    const float ig0 = sigm_p(AI[0]) * gv0, ig1 = sigm_p(AI[1]) * gv1;   \
    const float ig2 = sigm_p(AI[2]) * gv2, ig3 = sigm_p(AI[3]) * gv3;   \
    AF = mfma16(a1, B1_1, AF); AO = mfma16(a1, B3_1, AO);               \
    AF = mfma16(a2, B1_2, AF); AO = mfma16(a2, B3_2, AO);               \
    AF = mfma16(a3, B1_3, AF); AO = mfma16(a3, B3_3, AO);               \
    AF = mfma16(a4, B1_4, AF); AO = mfma16(a4, B3_4, AO);               \
    AF = mfma16(a5, B1_5, AF); AO = mfma16(a5, B3_5, AO);               \
    AF = mfma16(a6, B1_6, AF); AO = mfma16(a6, B3_6, AO);               \
    short* hd_ = (((SUB) & 1) == 0) ? hw1 : hw0;                        \
    float hv0, hv1, hv2, hv3;                                           \
    {                                                                   \
        const float fv_ = sigm_p(AF[0]), ov_ = sigm_p(AO[0]);           \
        const float cn_ = fmaf(fv_, c0, ig0);                           \
        c0 = (FRZ) ? 0.0f : cn_;                                        \
        hv0 = ov_ * tanh_p(c0 * L2E2);                                  \
    }                                                                   \
    {                                                                   \
        const float fv_ = sigm_p(AF[1]), ov_ = sigm_p(AO[1]);           \
        const float cn_ = fmaf(fv_, c1, ig1);                           \
        c1 = (FRZ) ? 0.0f : cn_;                                        \
        hv1 = ov_ * tanh_p(c1 * L2E2);                                  \
    }                                                                   \
    {                                                                   \
        const float fv_ = sigm_p(AF[2]), ov_ = sigm_p(AO[2]);           \
        const float cn_ = fmaf(fv_, c2, ig2);                           \
        c2 = (FRZ) ? 0.0f : cn_;                                        \
        hv2 = ov_ * tanh_p(c2 * L2E2);                                  \
    }                                                                   \
    {                                                                   \
        const float fv_ = sigm_p(AF[3]), ov_ = sigm_p(AO[3]);           \
        const float cn_ = fmaf(fv_, c3, ig3);                           \
        c3 = (FRZ) ? 0.0f : cn_;                                        \
        hv3 = ov_ * tanh_p(c3 * L2E2);                                  \
    }                                                                   \
    const unsigned pA_ = pkbf(hv0, hv1);                                \
    const unsigned pB_ = pkbf(hv2, hv3);                                \
    hd_[0]   = (short)pA_; hd_[72]  = (short)(pA_ >> 16);               \
    hd_[144] = (short)pB_; hd_[216] = (short)(pB_ >> 16);               \
    a0c = *(const bf16x8*)(XNXT);   /* next step's x frag: buffer stable */ \
    SGB(0x100, 7, 0);               /* 7 ds_read first (6 frags + a0c)  */ \
    SGB(0x008, 16, 0);              /* 4 x-MFMAs + G/I chains           */ \
    SGB(0x008, 2, 0); SGB(0x002, 5, 0);   /* F/O pair ; g/i act ops     */ \
    SGB(0x008, 2, 0); SGB(0x002, 5, 0);                                 \
    SGB(0x008, 2, 0); SGB(0x002, 5, 0);                                 \
    SGB(0x008, 2, 0); SGB(0x002, 5, 0);                                 \
    SGB(0x008, 2, 0); SGB(0x002, 5, 0);                                 \
    SGB(0x008, 2, 0); SGB(0x002, 5, 0);                                 \
    if (XST) {                                                          \
        short4v pa_; pa_[0] = f2bf(xr0.x); pa_[1] = f2bf(xr0.y);        \
        pa_[2] = f2bf(xr0.z); pa_[3] = f2bf(xr0.w);                     \
        *(short4v*)(xsW) = pa_;                                         \
        short4v pb_; pb_[0] = f2bf(xr1.x); pb_[1] = f2bf(xr1.y);        \
        pb_[2] = f2bf(xr1.z); pb_[3] = f2bf(xr1.w);                     \
        *(short4v*)(xsW + 16) = pb_;                                    \
    }                                                                   \
    asm volatile("s_waitcnt lgkmcnt(0)" ::: "memory");                  \
    __builtin_amdgcn_s_barrier();                                       \
} while (0)

__global__ __launch_bounds__(256)
void lstm_mfma_68547678044465(const float* __restrict__ x,
                              const float* __restrict__ Wih0, const float* __restrict__ Whh0,
                              const float* __restrict__ bih0, const float* __restrict__ bhh0,
                              const float* __restrict__ Wih1, const float* __restrict__ Whh1,
                              const float* __restrict__ bih1, const float* __restrict__ bhh1,
                              const float* __restrict__ ln_g, const float* __restrict__ ln_b,
                              const float* __restrict__ fcw, const float* __restrict__ fcb,
                              float* __restrict__ out)
{
    __shared__ __align__(16) short XB[2][8][16][40];  // x bf16; rows 8-15 always zero
    __shared__ __align__(16) short HA[2][24][72];     // rows 0-7 zero | 8-15 h0 | 16-23 zero
    __shared__ __align__(16) short HC[2][16][72];     // rows 0-7 zero | 8-15 h1
    __shared__ __align__(16) float HF[8][64];         // final h1 fp32 for LN

    const int tid  = threadIdx.x;
    const int wl   = tid >> 6;           // wave 0..3
    const int lane = tid & 63;
    const int n    = lane & 15;          // A row m / C col n
    const int q    = lane >> 4;          // k-quad / C row group
    const int rb   = blockIdx.x * RPB;
    const int cell = wl * 16 + n;        // h-dim cell 0..63
    const bool qhi = (q >= 2);

    // ---- B-fragments: 4 gate-tiles x 7 K-chunks, named registers ----
    auto loadB = [&](const float* wrow, float sc) -> bf16x8 {
        const float4 lo = *(const float4*)(wrow);
        const float4 hi = *(const float4*)(wrow + 4);
        short8 r;
        r[0] = f2bf(lo.x * sc); r[1] = f2bf(lo.y * sc);
        r[2] = f2bf(lo.z * sc); r[3] = f2bf(lo.w * sc);
        r[4] = f2bf(hi.x * sc); r[5] = f2bf(hi.y * sc);
        r[6] = f2bf(hi.z * sc); r[7] = f2bf(hi.w * sc);
        return (bf16x8)r;
    };
    const int g0 = cell, g1 = 64 + cell, g2 = 128 + cell, g3 = 192 + cell;
    const int ko = q * 8;
    const bf16x8 B0_0 = loadB(Wih0 + g0 * 32 + ko, L2E);
    const bf16x8 B0_1 = loadB(Whh0 + g0 * 64 + ko, L2E);
    const bf16x8 B0_2 = loadB(Whh0 + g0 * 64 + 32 + ko, L2E);
    const bf16x8 B0_3 = loadB(Wih1 + g0 * 64 + ko, L2E);
    const bf16x8 B0_4 = loadB(Wih1 + g0 * 64 + 32 + ko, L2E);
    const bf16x8 B0_5 = loadB(Whh1 + g0 * 64 + ko, L2E);
    const bf16x8 B0_6 = loadB(Whh1 + g0 * 64 + 32 + ko, L2E);
    const bf16x8 B1_0 = loadB(Wih0 + g1 * 32 + ko, L2E);
    const bf16x8 B1_1 = loadB(Whh0 + g1 * 64 + ko, L2E);
    const bf16x8 B1_2 = loadB(Whh0 + g1 * 64 + 32 + ko, L2E);
    const bf16x8 B1_3 = loadB(Wih1 + g1 * 64 + ko, L2E);
    const bf16x8 B1_4 = loadB(Wih1 + g1 * 64 + 32 + ko, L2E);
    const bf16x8 B1_5 = loadB(Whh1 + g1 * 64 + ko, L2E);
    const bf16x8 B1_6 = loadB(Whh1 + g1 * 64 + 32 + ko, L2E);
    const bf16x8 B2_0 = loadB(Wih0 + g2 * 32 + ko, L2E2);
    const bf16x8 B2_1 = loadB(Whh0 + g2 * 64 + ko, L2E2);
    const bf16x8 B2_2 = loadB(Whh0 + g2 * 64 + 32 + ko, L2E2);
    const bf16x8 B2_3 = loadB(Wih1 + g2 * 64 + ko, L2E2);
    const bf16x8 B2_4 = loadB(Wih1 + g2 * 64 + 32 + ko, L2E2);
    const bf16x8 B2_5 = loadB(Whh1 + g2 * 64 + ko, L2E2);
    const bf16x8 B2_6 = loadB(Whh1 + g2 * 64 + 32 + ko, L2E2);
    const bf16x8 B3_0 = loadB(Wih0 + g3 * 32 + ko, L2E);
    const bf16x8 B3_1 = loadB(Whh0 + g3 * 64 + ko, L2E);
    const bf16x8 B3_2 = loadB(Whh0 + g3 * 64 + 32 + ko, L2E);
    const bf16x8 B3_3 = loadB(Wih1 + g3 * 64 + ko, L2E);
    const bf16x8 B3_4 = loadB(Wih1 + g3 * 64 + 32 + ko, L2E);
    const bf16x8 B3_5 = loadB(Whh1 + g3 * 64 + ko, L2E);
    const bf16x8 B3_6 = loadB(Whh1 + g3 * 64 + 32 + ko, L2E);

    // ---- biases: per-lane layer select (q<2 -> L0 rows, q>=2 -> L1 rows) ----
    float b0, b1, b2, b3;
    if (!qhi) {
        b0 = (bih0[g0] + bhh0[g0]) * L2E;  b1 = (bih0[g1] + bhh0[g1]) * L2E;
        b2 = (bih0[g2] + bhh0[g2]) * L2E2; b3 = (bih0[g3] + bhh0[g3]) * L2E;
    } else {
        b0 = (bih1[g0] + bhh1[g0]) * L2E;  b1 = (bih1[g1] + bhh1[g1]) * L2E;
        b2 = (bih1[g2] + bhh1[g2]) * L2E2; b3 = (bih1[g3] + bhh1[g3]) * L2E;
    }

    // ---- zero all LDS (zero rows must stay zero; parity bufs start 0) ----
    { int* z = (int*)XB; for (int i = tid; i < 5120; i += 256) z[i] = 0; }
    { int* z = (int*)HA; for (int i = tid; i < 1728; i += 256) z[i] = 0; }
    { int* z = (int*)HC; for (int i = tid; i < 1152; i += 256) z[i] = 0; }

    // ---- per-lane invariant LDS pointers / offsets ----
    const short* haA = &HA[0][0][0];
    const short* haB = &HA[1][0][0];
    const short* hcA = &HC[0][0][0];
    const short* hcB = &HC[1][0][0];
    const int oH1 = (8 + n) * 72 + q * 8;     // h0 rows 8+m (L0 side)
    const int oH2 = n * 72 + q * 8;           // rows m (zero pad | data)
    const short* xb0 = &XB[0][0][0][0] + (n * 40 + q * 8);
    const short* xb1 = xb0 + 5120;
    short* hw0 = (qhi ? &HC[0][8 + (q & 1) * 4][0]
                      : &HA[0][8 + (q & 1) * 4][0]) + cell;   // parity-0 target
    short* hw1 = (qhi ? &HC[1][8 + (q & 1) * 4][0]
                      : &HA[1][8 + (q & 1) * 4][0]) + cell;   // parity-1 target

    // ---- x staging: thread -> (step ss, row sm, quad kq), 2 float4 each ----
    const int ss = tid >> 5, sm = (tid >> 2) & 7, kq = tid & 3;
    const float* xrow = x + (size_t)(rb + sm) * (TSTEPS * 32);
    short* xs0 = &XB[0][ss][sm][0] + kq * 4;
    short* xs1 = xs0 + 5120;
    const float* xp = xrow + (8 + ss) * 32 + kq * 4;   // group-1 prefetch base
    float4 xr0 = *(const float4*)(xrow + ss * 32 + kq * 4);
    float4 xr1 = *(const float4*)(xrow + ss * 32 + kq * 4 + 16);
    {   // initial stage of group 0 into buf 0
        short4v pa; pa[0] = f2bf(xr0.x); pa[1] = f2bf(xr0.y);
        pa[2] = f2bf(xr0.z); pa[3] = f2bf(xr0.w);
        *(short4v*)(xs0) = pa;
        short4v pb; pb[0] = f2bf(xr1.x); pb[1] = f2bf(xr1.y);
        pb[2] = f2bf(xr1.z); pb[3] = f2bf(xr1.w);
        *(short4v*)(xs0 + 16) = pb;
    }
    __syncthreads();

    float c0 = 0.0f, c1 = 0.0f, c2 = 0.0f, c3 = 0.0f;
    bf16x8 a0c = *(const bf16x8*)(xb0);       // x frag for step 0

#pragma unroll 1
    for (int g = 0; g < 64; ++g) {
        const short* xbR = (g & 1) ? xb1 : xb0;   // read buf = g&1
        const short* xbO = (g & 1) ? xb0 : xb1;   // other buf (next group)
        short* xsW       = (g & 1) ? xs0 : xs1;   // stage target = (g+1)&1
        const bool fz = (g == 0) && qhi;          // phantom L1 step -1
        const bool pg = (g < 63);
        STEPB(0, pg, 0, fz,    xbR + 640);
        STEPB(1, 0, 0, false,  xbR + 1280);
        STEPB(2, 0, 0, false,  xbR + 1920);
        STEPB(3, 0, 0, false,  xbR + 2560);
        STEPB(4, 0, 0, false,  xbR + 3200);
        STEPB(5, 0, 0, false,  xbR + 3840);
        STEPB(6, 0, pg, false, xbR + 4480);
        STEPB(7, 0, 0, false,  xbO);
        xp += 256;                                // next group's prefetch base
    }

    // ---- peeled epilogue step (it = TSTEPS): only L1 (q>=2) results used.
    // a0c holds stale buf-0 x data (finite garbage) -> L0 lanes' values unused.
    {
        const bf16x8 a1 = *(const bf16x8*)(haA + oH1);
        const bf16x8 a2 = *(const bf16x8*)(haA + oH1 + 32);
        const bf16x8 a3 = *(const bf16x8*)(haA + oH2);
        const bf16x8 a4 = *(const bf16x8*)(haA + oH2 + 32);
        const bf16x8 a5 = *(const bf16x8*)(hcA + oH2);
        const bf16x8 a6 = *(const bf16x8*)(hcA + oH2 + 32);
        f32x4 AG = {b2, b2, b2, b2}, AI = {b0, b0, b0, b0},
              AF = {b1, b1, b1, b1}, AO = {b3, b3, b3, b3};
        AG = mfma16(a0c, B2_0, AG); AI = mfma16(a0c, B0_0, AI);
        AF = mfma16(a0c, B1_0, AF); AO = mfma16(a0c, B3_0, AO);
        AG = mfma16(a1, B2_1, AG); AI = mfma16(a1, B0_1, AI);
        AG = mfma16(a2, B2_2, AG); AI = mfma16(a2, B0_2, AI);
        AG = mfma16(a3, B2_3, AG); AI = mfma16(a3, B0_3, AI);
        AG = mfma16(a4, B2_4, AG); AI = mfma16(a4, B0_4, AI);
        AG = mfma16(a5, B2_5, AG); AI = mfma16(a5, B0_5, AI);
        AG = mfma16(a6, B2_6, AG); AI = mfma16(a6, B0_6, AI);
        AF = mfma16(a1, B1_1, AF); AO = mfma16(a1, B3_1, AO);
        AF = mfma16(a2, B1_2, AF); AO = mfma16(a2, B3_2, AO);
        AF = mfma16(a3, B1_3, AF); AO = mfma16(a3, B3_3, AO);
        AF = mfma16(a4, B1_4, AF); AO = mfma16(a4, B3_4, AO);
        AF = mfma16(a5, B1_5, AF); AO = mfma16(a5, B3_5, AO);
        AF = mfma16(a6, B1_6, AF); AO = mfma16(a6, B3_6, AO);
        const float gv0 = tanh_p(AG[0]), gv1 = tanh_p(AG[1]);
        const float gv2 = tanh_p(AG[2]), gv3 = tanh_p(AG[3]);
        const float ig0 = sigm_p(AI[0]) * gv0, ig1 = sigm_p(AI[1]) * gv1;
        const float ig2 = sigm_p(AI[2]) * gv2, ig3 = sigm_p(AI[3]) * gv3;
        float hv0, hv1, hv2, hv3;
        {
            const float fv_ = sigm_p(AF[0]), ov_ = sigm_p(AO[0]);
            c0 = fmaf(fv_, c0, ig0); hv0 = ov_ * tanh_p(c0 * L2E2);
        }
        {
            const float fv_ = sigm_p(AF[1]), ov_ = sigm_p(AO[1]);
            c1 = fmaf(fv_, c1, ig1); hv1 = ov_ * tanh_p(c1 * L2E2);
        }
        {
            const float fv_ = sigm_p(AF[2]), ov_ = sigm_p(AO[2]);
            c2 = fmaf(fv_, c2, ig2); hv2 = ov_ * tanh_p(c2 * L2E2);
        }
        {
            const float fv_ = sigm_p(AF[3]), ov_ = sigm_p(AO[3]);
            c3 = fmaf(fv_, c3, ig3); hv3 = ov_ * tanh_p(c3 * L2E2);
        }
        if (qhi) {                              // final h1 (step T-1), fp32
            const int rl = (q & 1) * 4;
            HF[rl + 0][cell] = hv0;
            HF[rl + 1][cell] = hv1;
            HF[rl + 2][cell] = hv2;
            HF[rl + 3][cell] = hv3;
        }
    }
    __syncthreads();

    // ---- epilogue: LayerNorm + FC; each wave handles 2 rows ----
    const float lg = ln_g[lane], lb = ln_b[lane], fw = fcw[lane], fb = fcb[0];
#pragma unroll
    for (int rr = 0; rr < 2; ++rr) {
        const int row = wl * 2 + rr;
        const float v = HF[row][lane];
        float s1 = v, sq = v * v;
#pragma unroll
        for (int mm = 1; mm < 64; mm <<= 1) {
            s1 += __shfl_xor(s1, mm, 64);
            sq += __shfl_xor(sq, mm, 64);
        }
        const float mu = s1 * (1.0f / 64.0f);
        float var = sq * (1.0f / 64.0f) - mu * mu;
        var = fmaxf(var, 0.0f);
        const float rs = rsqrtf(var + 1e-5f);
        float pv = ((v - mu) * rs * lg + lb) * fw;
#pragma unroll
        for (int mm = 1; mm < 64; mm <<= 1) pv += __shfl_xor(pv, mm, 64);
        if (lane == 0) out[rb + row] = pv + fb;
    }
}

extern "C" void kernel_launch(void* const* d_in, const int* in_sizes, int n_in,
                              void* d_out, int out_size, void* d_ws, size_t ws_size,
                              hipStream_t stream) {
    const float* x    = (const float*)d_in[0];
    const float* Wih0 = (const float*)d_in[1];
    const float* Whh0 = (const float*)d_in[2];
    const float* bih0 = (const float*)d_in[3];
    const float* bhh0 = (const float*)d_in[4];
    const float* Wih1 = (const float*)d_in[5];
    const float* Whh1 = (const float*)d_in[6];
    const float* bih1 = (const float*)d_in[7];
    const float* bhh1 = (const float*)d_in[8];
    const float* ln_g = (const float*)d_in[9];
    const float* ln_b = (const float*)d_in[10];
    const float* fcw  = (const float*)d_in[11];
    const float* fcb  = (const float*)d_in[12];

    dim3 grid(2048 / RPB);    // 256 blocks -> 1 per CU
    dim3 block(256);          // 4 waves: 1 per SIMD
    hipLaunchKernelGGL(lstm_mfma_68547678044465, grid, block, 0, stream,
                       x, Wih0, Whh0, bih0, bhh0, Wih1, Whh1, bih1, bhh1,
                       ln_g, ln_b, fcw, fcb, (float*)d_out);
}

// Round 8
// 445.943 us; speedup vs baseline: 1.0435x; 1.0435x over previous
//
#include <hip/hip_runtime.h>
#include <math.h>

#define TSTEPS 512
#define RPB 8
#define L2E  1.4426950408889634f
#define L2E2 2.8853900817779268f   // 2*log2(e)

typedef __attribute__((ext_vector_type(4))) short short4v;
typedef __attribute__((ext_vector_type(8))) short short8;
typedef __attribute__((ext_vector_type(4))) float f32x4;
typedef __bf16 bf16x8 __attribute__((ext_vector_type(8)));

__device__ __forceinline__ short f2bf(float f) {            // RNE float->bf16
    union { float f; unsigned u; } v; v.f = f;
    return (short)((v.u + 0x7FFFu + ((v.u >> 16) & 1u)) >> 16);
}
__device__ __forceinline__ unsigned pkbf(float lo, float hi) {  // HW RNE pack
    unsigned r;
    asm("v_cvt_pk_bf16_f32 %0, %1, %2" : "=v"(r) : "v"(lo), "v"(hi));
    return r;
}
__device__ __forceinline__ float rcp_f(float x) { return __builtin_amdgcn_rcpf(x); }
__device__ __forceinline__ float ex2(float x)   { return __builtin_amdgcn_exp2f(x); }
__device__ __forceinline__ float sigm_p(float v) { return rcp_f(1.0f + ex2(-v)); }   // v = x*log2e
__device__ __forceinline__ float tanh_p(float v) {                                    // v = x*2log2e
    return fmaf(-2.0f, rcp_f(1.0f + ex2(v)), 1.0f);        // 1 - 2/(1+e^{2x})
}
__device__ __forceinline__ f32x4 mfma16(bf16x8 a, bf16x8 b, f32x4 c) {
    return __builtin_amdgcn_mfma_f32_16x16x32_bf16(a, b, c, 0, 0, 0);
}

// 256 blocks x 256 threads (4 waves, 1/SIMD). Merged 16x16 MFMA tile,
// K=224 block-diagonal:
//   A rows 0-7  = [x_t (32) | h0^{t-1} (64) | 0 (128)]        -> L0 step t
//   A rows 8-15 = [0 (96)   | h0 (64)       | h1 (64)]        -> L1 (lag 2!)
// LAG-2 PIPELINE. Iteration j computes L0-step j and L1-step j-2. Of the 7
// K-chunks, only chunks 1,2 (h0^{j-1}, L0 rows) and 5,6 (h1^{j-3}, L1
// recurrent) need barrier-fresh data. Chunk 0 (x_{j+1}) and chunks 3,4
// (h0^{j-1} = L1-input for step j-1, SAME buffer as chunks 1,2) are
// accumulated into NEXT-step accs during iteration j's activation window
// -> post-barrier critical chain shrinks from 28 MFMAs (2x2-way chains) to
// 16 MFMAs (4-way interleaved, issue-bound), and the h-write drain +
// barrier wait get real MFMA filler. Zero-block MFMAs contribute exact +-0
// in unchanged relative order -> BIT-IDENTICAL output. Freeze covers j in
// {0,1} (phantom L1 steps -2,-1). Tail: j=512,513 run garbage L0 steps
// (bounded: sigmoid/tanh outputs, no NaN possible), confined to L0 rows /
// q<2 lanes; L1 finishes step 511 at j=513.
#define STEPB(SUB, PREF, XST, FRZ, XNXT, XG, XI, XF, XO, YG, YI, YF, YO) do { \
    const short* haS_ = ((SUB) & 1) ? haB : haA;                        \
    const short* hcS_ = ((SUB) & 1) ? hcB : hcA;                        \
    /* cur-acc fresh frags */                                           \
    const bf16x8 a1 = *(const bf16x8*)(haS_ + oH1);                     \
    const bf16x8 a2 = *(const bf16x8*)(haS_ + oH1 + 32);                \
    const bf16x8 a5 = *(const bf16x8*)(hcS_ + oH2);                     \
    const bf16x8 a6 = *(const bf16x8*)(hcS_ + oH2 + 32);                \
    /* next-acc frags (stable data: same-buffer h0 rows m, next x) */   \
    const bf16x8 a3 = *(const bf16x8*)(haS_ + oH2);                     \
    const bf16x8 a4 = *(const bf16x8*)(haS_ + oH2 + 32);                \
    const bf16x8 a0n = *(const bf16x8*)(XNXT);                          \
    if (PREF) {                                                         \
        xr0 = *(const float4*)(xp);                                     \
        xr1 = *(const float4*)(xp + 16);                                \
    }                                                                   \
    /* next-acc init + chunk 0: independent, fills a1 ds latency */     \
    YG = (f32x4){b2, b2, b2, b2}; YI = (f32x4){b0, b0, b0, b0};         \
    YF = (f32x4){b1, b1, b1, b1}; YO = (f32x4){b3, b3, b3, b3};         \
    YG = mfma16(a0n, B2_0, YG); YI = mfma16(a0n, B0_0, YI);             \
    YF = mfma16(a0n, B1_0, YF); YO = mfma16(a0n, B3_0, YO);             \
    /* cur-acc completion: 16 MFMAs, 4-way interleaved */               \
    XG = mfma16(a1, B2_1, XG); XI = mfma16(a1, B0_1, XI);               \
    XF = mfma16(a1, B1_1, XF); XO = mfma16(a1, B3_1, XO);               \
    XG = mfma16(a2, B2_2, XG); XI = mfma16(a2, B0_2, XI);               \
    XF = mfma16(a2, B1_2, XF); XO = mfma16(a2, B3_2, XO);               \
    XG = mfma16(a5, B2_5, XG); XI = mfma16(a5, B0_5, XI);               \
    XF = mfma16(a5, B1_5, XF); XO = mfma16(a5, B3_5, XO);               \
    XG = mfma16(a6, B2_6, XG); XI = mfma16(a6, B0_6, XI);               \
    XF = mfma16(a6, B1_6, XF); XO = mfma16(a6, B3_6, XO);               \
    /* g/i activations */                                               \
    const float gv0 = tanh_p(XG[0]), gv1 = tanh_p(XG[1]);               \
    const float gv2 = tanh_p(XG[2]), gv3 = tanh_p(XG[3]);               \
    const float ig0 = sigm_p(XI[0]) * gv0, ig1 = sigm_p(XI[1]) * gv1;   \
    const float ig2 = sigm_p(XI[2]) * gv2, ig3 = sigm_p(XI[3]) * gv3;   \
    /* next-acc chunks 3,4 (h0 as L1 input): fills act window */        \
    YG = mfma16(a3, B2_3, YG); YI = mfma16(a3, B0_3, YI);               \
    YF = mfma16(a3, B1_3, YF); YO = mfma16(a3, B3_3, YO);               \
    YG = mfma16(a4, B2_4, YG); YI = mfma16(a4, B0_4, YI);               \
    YF = mfma16(a4, B1_4, YF); YO = mfma16(a4, B3_4, YO);               \
    /* f/o/c/h */                                                       \
    short* hd_ = (((SUB) & 1) == 0) ? hw1 : hw0;                        \
    float hv0, hv1, hv2, hv3;                                           \
    {                                                                   \
        const float fv_ = sigm_p(XF[0]), ov_ = sigm_p(XO[0]);           \
        const float cn_ = fmaf(fv_, c0, ig0);                           \
        c0 = (FRZ) ? 0.0f : cn_;                                        \
        hv0 = ov_ * tanh_p(c0 * L2E2);                                  \
    }                                                                   \
    {                                                                   \
        const float fv_ = sigm_p(XF[1]), ov_ = sigm_p(XO[1]);           \
        const float cn_ = fmaf(fv_, c1, ig1);                           \
        c1 = (FRZ) ? 0.0f : cn_;                                        \
        hv1 = ov_ * tanh_p(c1 * L2E2);                                  \
    }                                                                   \
    {                                                                   \
        const float fv_ = sigm_p(XF[2]), ov_ = sigm_p(XO[2]);           \
        const float cn_ = fmaf(fv_, c2, ig2);                           \
        c2 = (FRZ) ? 0.0f : cn_;                                        \
        hv2 = ov_ * tanh_p(c2 * L2E2);                                  \
    }                                                                   \
    {                                                                   \
        const float fv_ = sigm_p(XF[3]), ov_ = sigm_p(XO[3]);           \
        const float cn_ = fmaf(fv_, c3, ig3);                           \
        c3 = (FRZ) ? 0.0f : cn_;                                        \
        hv3 = ov_ * tanh_p(c3 * L2E2);                                  \
    }                                                                   \
    const unsigned pA_ = pkbf(hv0, hv1);                                \
    const unsigned pB_ = pkbf(hv2, hv3);                                \
    hd_[0]   = (short)pA_; hd_[72]  = (short)(pA_ >> 16);               \
    hd_[144] = (short)pB_; hd_[216] = (short)(pB_ >> 16);               \
    if (XST) {                                                          \
        short4v pa_; pa_[0] = f2bf(xr0.x); pa_[1] = f2bf(xr0.y);        \
        pa_[2] = f2bf(xr0.z); pa_[3] = f2bf(xr0.w);                     \
        *(short4v*)(xsW) = pa_;                                         \
        short4v pb_; pb_[0] = f2bf(xr1.x); pb_[1] = f2bf(xr1.y);        \
        pb_[2] = f2bf(xr1.z); pb_[3] = f2bf(xr1.w);                     \
        *(short4v*)(xsW + 16) = pb_;                                    \
    }                                                                   \
    asm volatile("s_waitcnt lgkmcnt(0)" ::: "memory");                  \
    __builtin_amdgcn_s_barrier();                                       \
} while (0)

__global__ __launch_bounds__(256)
void lstm_mfma_68547678044465(const float* __restrict__ x,
                              const float* __restrict__ Wih0, const float* __restrict__ Whh0,
                              const float* __restrict__ bih0, const float* __restrict__ bhh0,
                              const float* __restrict__ Wih1, const float* __restrict__ Whh1,
                              const float* __restrict__ bih1, const float* __restrict__ bhh1,
                              const float* __restrict__ ln_g, const float* __restrict__ ln_b,
                              const float* __restrict__ fcw, const float* __restrict__ fcb,
                              float* __restrict__ out)
{
    __shared__ __align__(16) short XB[2][8][16][40];  // x bf16; rows 8-15 always zero
    __shared__ __align__(16) short HA[2][24][72];     // rows 0-7 zero | 8-15 h0 | 16-23 zero
    __shared__ __align__(16) short HC[2][16][72];     // rows 0-7 zero | 8-15 h1
    __shared__ __align__(16) float HF[8][64];         // final h1 fp32 for LN

    const int tid  = threadIdx.x;
    const int wl   = tid >> 6;           // wave 0..3
    const int lane = tid & 63;
    const int n    = lane & 15;          // A row m / C col n
    const int q    = lane >> 4;          // k-quad / C row group
    const int rb   = blockIdx.x * RPB;
    const int cell = wl * 16 + n;        // h-dim cell 0..63
    const bool qhi = (q >= 2);

    // ---- B-fragments: 4 gate-tiles x 7 K-chunks, named registers ----
    auto loadB = [&](const float* wrow, float sc) -> bf16x8 {
        const float4 lo = *(const float4*)(wrow);
        const float4 hi = *(const float4*)(wrow + 4);
        short8 r;
        r[0] = f2bf(lo.x * sc); r[1] = f2bf(lo.y * sc);
        r[2] = f2bf(lo.z * sc); r[3] = f2bf(lo.w * sc);
        r[4] = f2bf(hi.x * sc); r[5] = f2bf(hi.y * sc);
        r[6] = f2bf(hi.z * sc); r[7] = f2bf(hi.w * sc);
        return (bf16x8)r;
    };
    const int g0 = cell, g1 = 64 + cell, g2 = 128 + cell, g3 = 192 + cell;
    const int ko = q * 8;
    const bf16x8 B0_0 = loadB(Wih0 + g0 * 32 + ko, L2E);
    const bf16x8 B0_1 = loadB(Whh0 + g0 * 64 + ko, L2E);
    const bf16x8 B0_2 = loadB(Whh0 + g0 * 64 + 32 + ko, L2E);
    const bf16x8 B0_3 = loadB(Wih1 + g0 * 64 + ko, L2E);
    const bf16x8 B0_4 = loadB(Wih1 + g0 * 64 + 32 + ko, L2E);
    const bf16x8 B0_5 = loadB(Whh1 + g0 * 64 + ko, L2E);
    const bf16x8 B0_6 = loadB(Whh1 + g0 * 64 + 32 + ko, L2E);
    const bf16x8 B1_0 = loadB(Wih0 + g1 * 32 + ko, L2E);
    const bf16x8 B1_1 = loadB(Whh0 + g1 * 64 + ko, L2E);
    const bf16x8 B1_2 = loadB(Whh0 + g1 * 64 + 32 + ko, L2E);
    const bf16x8 B1_3 = loadB(Wih1 + g1 * 64 + ko, L2E);
    const bf16x8 B1_4 = loadB(Wih1 + g1 * 64 + 32 + ko, L2E);
    const bf16x8 B1_5 = loadB(Whh1 + g1 * 64 + ko, L2E);
    const bf16x8 B1_6 = loadB(Whh1 + g1 * 64 + 32 + ko, L2E);
    const bf16x8 B2_0 = loadB(Wih0 + g2 * 32 + ko, L2E2);
    const bf16x8 B2_1 = loadB(Whh0 + g2 * 64 + ko, L2E2);
    const bf16x8 B2_2 = loadB(Whh0 + g2 * 64 + 32 + ko, L2E2);
    const bf16x8 B2_3 = loadB(Wih1 + g2 * 64 + ko, L2E2);
    const bf16x8 B2_4 = loadB(Wih1 + g2 * 64 + 32 + ko, L2E2);
    const bf16x8 B2_5 = loadB(Whh1 + g2 * 64 + ko, L2E2);
    const bf16x8 B2_6 = loadB(Whh1 + g2 * 64 + 32 + ko, L2E2);
    const bf16x8 B3_0 = loadB(Wih0 + g3 * 32 + ko, L2E);
    const bf16x8 B3_1 = loadB(Whh0 + g3 * 64 + ko, L2E);
    const bf16x8 B3_2 = loadB(Whh0 + g3 * 64 + 32 + ko, L2E);
    const bf16x8 B3_3 = loadB(Wih1 + g3 * 64 + ko, L2E);
    const bf16x8 B3_4 = loadB(Wih1 + g3 * 64 + 32 + ko, L2E);
    const bf16x8 B3_5 = loadB(Whh1 + g3 * 64 + ko, L2E);
    const bf16x8 B3_6 = loadB(Whh1 + g3 * 64 + 32 + ko, L2E);

    // ---- biases: per-lane layer select (q<2 -> L0 rows, q>=2 -> L1 rows) ----
    float b0, b1, b2, b3;
    if (!qhi) {
        b0 = (bih0[g0] + bhh0[g0]) * L2E;  b1 = (bih0[g1] + bhh0[g1]) * L2E;
        b2 = (bih0[g2] + bhh0[g2]) * L2E2; b3 = (bih0[g3] + bhh0[g3]) * L2E;
    } else {
        b0 = (bih1[g0] + bhh1[g0]) * L2E;  b1 = (bih1[g1] + bhh1[g1]) * L2E;
        b2 = (bih1[g2] + bhh1[g2]) * L2E2; b3 = (bih1[g3] + bhh1[g3]) * L2E;
    }

    // ---- zero all LDS (zero rows must stay zero; parity bufs start 0) ----
    { int* z = (int*)XB; for (int i = tid; i < 5120; i += 256) z[i] = 0; }
    { int* z = (int*)HA; for (int i = tid; i < 1728; i += 256) z[i] = 0; }
    { int* z = (int*)HC; for (int i = tid; i < 1152; i += 256) z[i] = 0; }

    // ---- per-lane invariant LDS pointers / offsets ----
    const short* haA = &HA[0][0][0];
    const short* haB = &HA[1][0][0];
    const short* hcA = &HC[0][0][0];
    const short* hcB = &HC[1][0][0];
    const int oH1 = (8 + n) * 72 + q * 8;     // h0 rows 8+m (L0 side)
    const int oH2 = n * 72 + q * 8;           // rows m (zero pad | data)
    const short* xb0 = &XB[0][0][0][0] + (n * 40 + q * 8);
    const short* xb1 = xb0 + 5120;
    short* hw0 = (qhi ? &HC[0][8 + (q & 1) * 4][0]
                      : &HA[0][8 + (q & 1) * 4][0]) + cell;   // parity-0 target
    short* hw1 = (qhi ? &HC[1][8 + (q & 1) * 4][0]
                      : &HA[1][8 + (q & 1) * 4][0]) + cell;   // parity-1 target

    // ---- x staging: thread -> (step ss, row sm, quad kq), 2 float4 each ----
    const int ss = tid >> 5, sm = (tid >> 2) & 7, kq = tid & 3;
    const float* xrow = x + (size_t)(rb + sm) * (TSTEPS * 32);
    short* xs0 = &XB[0][ss][sm][0] + kq * 4;
    short* xs1 = xs0 + 5120;
    const float* xp = xrow + (8 + ss) * 32 + kq * 4;   // group-1 prefetch base
    float4 xr0 = *(const float4*)(xrow + ss * 32 + kq * 4);
    float4 xr1 = *(const float4*)(xrow + ss * 32 + kq * 4 + 16);
    {   // initial stage of group 0 into buf 0
        short4v pa; pa[0] = f2bf(xr0.x); pa[1] = f2bf(xr0.y);
        pa[2] = f2bf(xr0.z); pa[3] = f2bf(xr0.w);
        *(short4v*)(xs0) = pa;
        short4v pb; pb[0] = f2bf(xr1.x); pb[1] = f2bf(xr1.y);
        pb[2] = f2bf(xr1.z); pb[3] = f2bf(xr1.w);
        *(short4v*)(xs0 + 16) = pb;
    }
    __syncthreads();

    float c0 = 0.0f, c1 = 0.0f, c2 = 0.0f, c3 = 0.0f;

    // ---- prologue: cur-accs for j=0 = bias + x_0 (chunks 3,4 are exact 0) ----
    f32x4 AG1 = {b2, b2, b2, b2}, AI1 = {b0, b0, b0, b0},
          AF1 = {b1, b1, b1, b1}, AO1 = {b3, b3, b3, b3};
    f32x4 AG2 = {0, 0, 0, 0}, AI2 = {0, 0, 0, 0},
          AF2 = {0, 0, 0, 0}, AO2 = {0, 0, 0, 0};
    {
        const bf16x8 a0p = *(const bf16x8*)(xb0);      // x_0 frag
        AG1 = mfma16(a0p, B2_0, AG1); AI1 = mfma16(a0p, B0_0, AI1);
        AF1 = mfma16(a0p, B1_0, AF1); AO1 = mfma16(a0p, B3_0, AO1);
    }

#pragma unroll 1
    for (int g = 0; g < 64; ++g) {
        const short* xbR = (g & 1) ? xb1 : xb0;   // read buf = g&1
        const short* xbO = (g & 1) ? xb0 : xb1;   // other buf (next group)
        short* xsW       = (g & 1) ? xs0 : xs1;   // stage target = (g+1)&1
        const bool fz = (g == 0) && qhi;          // phantom L1 steps -2,-1
        const bool pg = (g < 63);
        STEPB(0, pg, 0, fz,    xbR + 640,  AG1, AI1, AF1, AO1, AG2, AI2, AF2, AO2);
        STEPB(1, 0, 0, fz,     xbR + 1280, AG2, AI2, AF2, AO2, AG1, AI1, AF1, AO1);
        STEPB(2, 0, 0, false,  xbR + 1920, AG1, AI1, AF1, AO1, AG2, AI2, AF2, AO2);
        STEPB(3, 0, 0, false,  xbR + 2560, AG2, AI2, AF2, AO2, AG1, AI1, AF1, AO1);
        STEPB(4, 0, 0, false,  xbR + 3200, AG1, AI1, AF1, AO1, AG2, AI2, AF2, AO2);
        STEPB(5, 0, 0, false,  xbR + 3840, AG2, AI2, AF2, AO2, AG1, AI1, AF1, AO1);
        STEPB(6, 0, pg, false, xbR + 4480, AG1, AI1, AF1, AO1, AG2, AI2, AF2, AO2);
        STEPB(7, 0, 0, false,  xbO,        AG2, AI2, AF2, AO2, AG1, AI1, AF1, AO1);
        xp += 256;                                // next group's prefetch base
    }

    // ---- peeled j=512 (parity 0): L0 garbage step (bounded), L1-step 510.
    // Next-accs get x garbage (L0 rows only) + h0^{511} (real, L1 rows).
    {
        short* xsW = xs0;   // unused (XST=0); scoped alias for macro expansion
        STEPB(0, 0, 0, false, xb0, AG1, AI1, AF1, AO1, AG2, AI2, AF2, AO2);
    }

    // ---- peeled j=513 (parity 1): finish L1-step 511; only q>=2 used ----
    {
        const bf16x8 a1 = *(const bf16x8*)(haB + oH1);
        const bf16x8 a2 = *(const bf16x8*)(haB + oH1 + 32);
        const bf16x8 a5 = *(const bf16x8*)(hcB + oH2);
        const bf16x8 a6 = *(const bf16x8*)(hcB + oH2 + 32);
        AG2 = mfma16(a1, B2_1, AG2); AI2 = mfma16(a1, B0_1, AI2);
        AF2 = mfma16(a1, B1_1, AF2); AO2 = mfma16(a1, B3_1, AO2);
        AG2 = mfma16(a2, B2_2, AG2); AI2 = mfma16(a2, B0_2, AI2);
        AF2 = mfma16(a2, B1_2, AF2); AO2 = mfma16(a2, B3_2, AO2);
        AG2 = mfma16(a5, B2_5, AG2); AI2 = mfma16(a5, B0_5, AI2);
        AF2 = mfma16(a5, B1_5, AF2); AO2 = mfma16(a5, B3_5, AO2);
        AG2 = mfma16(a6, B2_6, AG2); AI2 = mfma16(a6, B0_6, AI2);
        AF2 = mfma16(a6, B1_6, AF2); AO2 = mfma16(a6, B3_6, AO2);
        const float gv0 = tanh_p(AG2[0]), gv1 = tanh_p(AG2[1]);
        const float gv2 = tanh_p(AG2[2]), gv3 = tanh_p(AG2[3]);
        const float ig0 = sigm_p(AI2[0]) * gv0, ig1 = sigm_p(AI2[1]) * gv1;
        const float ig2 = sigm_p(AI2[2]) * gv2, ig3 = sigm_p(AI2[3]) * gv3;
        float hv0, hv1, hv2, hv3;
        {
            const float fv_ = sigm_p(AF2[0]), ov_ = sigm_p(AO2[0]);
            c0 = fmaf(fv_, c0, ig0); hv0 = ov_ * tanh_p(c0 * L2E2);
        }
        {
            const float fv_ = sigm_p(AF2[1]), ov_ = sigm_p(AO2[1]);
            c1 = fmaf(fv_, c1, ig1); hv1 = ov_ * tanh_p(c1 * L2E2);
        }
        {
            const float fv_ = sigm_p(AF2[2]), ov_ = sigm_p(AO2[2]);
            c2 = fmaf(fv_, c2, ig2); hv2 = ov_ * tanh_p(c2 * L2E2);
        }
        {
            const float fv_ = sigm_p(AF2[3]), ov_ = sigm_p(AO2[3]);
            c3 = fmaf(fv_, c3, ig3); hv3 = ov_ * tanh_p(c3 * L2E2);
        }
        if (qhi) {                              // final h1 (step 511), fp32
            const int rl = (q & 1) * 4;
            HF[rl + 0][cell] = hv0;
            HF[rl + 1][cell] = hv1;
            HF[rl + 2][cell] = hv2;
            HF[rl + 3][cell] = hv3;
        }
    }
    __syncthreads();

    // ---- epilogue: LayerNorm + FC; each wave handles 2 rows ----
    const float lg = ln_g[lane], lb = ln_b[lane], fw = fcw[lane], fb = fcb[0];
#pragma unroll
    for (int rr = 0; rr < 2; ++rr) {
        const int row = wl * 2 + rr;
        const float v = HF[row][lane];
        float s1 = v, sq = v * v;
#pragma unroll
        for (int mm = 1; mm < 64; mm <<= 1) {
            s1 += __shfl_xor(s1, mm, 64);
            sq += __shfl_xor(sq, mm, 64);
        }
        const float mu = s1 * (1.0f / 64.0f);
        float var = sq * (1.0f / 64.0f) - mu * mu;
        var = fmaxf(var, 0.0f);
        const float rs = rsqrtf(var + 1e-5f);
        float pv = ((v - mu) * rs * lg + lb) * fw;
#pragma unroll
        for (int mm = 1; mm < 64; mm <<= 1) pv += __shfl_xor(pv, mm, 64);
        if (lane == 0) out[rb + row] = pv + fb;
    }
}

extern "C" void kernel_launch(void* const* d_in, const int* in_sizes, int n_in,
                              void* d_out, int out_size, void* d_ws, size_t ws_size,
                              hipStream_t stream) {
    const float* x    = (const float*)d_in[0];
    const float* Wih0 = (const float*)d_in[1];
    const float* Whh0 = (const float*)d_in[2];
    const float* bih0 = (const float*)d_in[3];
    const float* bhh0 = (const float*)d_in[4];
    const float* Wih1 = (const float*)d_in[5];
    const float* Whh1 = (const float*)d_in[6];
    const float* bih1 = (const float*)d_in[7];
    const float* bhh1 = (const float*)d_in[8];
    const float* ln_g = (const float*)d_in[9];
    const float* ln_b = (const float*)d_in[10];
    const float* fcw  = (const float*)d_in[11];
    const float* fcb  = (const float*)d_in[12];

    dim3 grid(2048 / RPB);    // 256 blocks -> 1 per CU
    dim3 block(256);          // 4 waves: 1 per SIMD
    hipLaunchKernelGGL(lstm_mfma_68547678044465, grid, block, 0, stream,
                       x, Wih0, Whh0, bih0, bhh0, Wih1, Whh1, bih1, bhh1,
                       ln_g, ln_b, fcw, fcb, (float*)d_out);
}